// Round 1
// baseline (254.410 us; speedup 1.0000x reference)
//
#include <hip/hip_runtime.h>
#include <hip/hip_bf16.h>
#include <math.h>

// Fused SelfAttention (attention over the HEADS axis, per token):
//   qkv = v @ [Wq|Wk|Wv]  (65536x256 @ 256x768, f16 MFMA)
//   per-token 8x8 softmax attention over heads (packed f16 + fp32 softmax)
//   out = x @ Wp + bp       (65536x256 @ 256x256, f16 MFMA)
//
// MFMA orientation: D = A*B, A = W^T-tile (rows = output col n), B = v^T-tile
// (cols = tokens). C/D layout: col(lane&15)=token, row(quad*4+r)=n.
// R5: v-operand register residency (16 f16x8 B-frags/wave) -> GEMM1 is a
// single 6-tile pass with zero LDS reads in the K-loop; ring-8 weight
// prefetch streams L2 with 8 loads in flight; GEMM2 ring-4 with prologue
// issued before the attention barrier. launch_bounds(512,4): 2 blocks/CU,
// <=128 VGPR. LDS layout/aliasing unchanged (v tile lives in q-section).

#define DIMX      256
#define NH        8
#define HD        32
#define TM        32       // tokens per block
#define NTHREADS  512      // 8 waves
#define QSTRIDE   776      // f16 units per row; 1552 B (16B aligned, banks ok)
#define KT        8        // 256/32 k-tiles
#define NT_QKV    48       // q: 0..15, k: 16..31, v: 32..47

typedef _Float16 f16x8 __attribute__((ext_vector_type(8)));
typedef _Float16 f16x4 __attribute__((ext_vector_type(4)));
typedef _Float16 f16x2 __attribute__((ext_vector_type(2)));
typedef float    f32x4 __attribute__((ext_vector_type(4)));

static __device__ __forceinline__ f16x2 pkrtz(float a, float b) {
    return (f16x2)__builtin_amdgcn_cvt_pkrtz(a, b);
}

// ---------------------------------------------------------------------------
// Prep: pack Wq|Wk|Wv and Wp into MFMA A-operand fragment order, fp32->f16.
// frag[j] = W[kt*32 + quad*8 + j][nt*16 + (lane&15)]
// packed index u = (nt*KT + kt)*64 + lane ; 8 f16 (16 B) per u, contiguous.
// ---------------------------------------------------------------------------
__global__ void pack_weights(const float* __restrict__ Wq,
                             const float* __restrict__ Wk,
                             const float* __restrict__ Wv,
                             const float* __restrict__ Wp,
                             _Float16* __restrict__ pk)
{
    const int QKV_FRAGS = NT_QKV * KT * 64;   // 24576
    int u = blockIdx.x * blockDim.x + threadIdx.x;  // 0..32767
    const float* W;
    int nt, kt, lane;
    if (u < QKV_FRAGS) {
        nt = u / (KT * 64); kt = (u / 64) % KT; lane = u % 64;
        if (nt < 16)      { W = Wq; }
        else if (nt < 32) { W = Wk; nt -= 16; }
        else              { W = Wv; nt -= 32; }
    } else {
        int u2 = u - QKV_FRAGS;
        nt = u2 / (KT * 64); kt = (u2 / 64) % KT; lane = u2 % 64;
        W = Wp;
    }
    const int n  = nt * 16 + (lane & 15);
    const int k0 = kt * 32 + (lane >> 4) * 8;
    f16x8 frag;
#pragma unroll
    for (int j = 0; j < 8; ++j)
        frag[j] = (_Float16)W[(size_t)(k0 + j) * DIMX + n];
    *(f16x8*)(pk + (size_t)u * 8) = frag;
}

// ---------------------------------------------------------------------------
// Main fused kernel. LDS: single 32x776 f16 region.
//   phase A: v tile in cols [0,256); phase B: q|k|vv in cols [0,768);
//   phase C: x tile overwrites q-section cols [0,256).
// ---------------------------------------------------------------------------
__global__ __launch_bounds__(NTHREADS, 4)   // 4 waves/EU -> 2 blocks/CU, <=128 VGPR
void fused_attn_mfma(const float* __restrict__ v,
                     const _Float16* __restrict__ Wqkv_pk,
                     const _Float16* __restrict__ Wp_pk,
                     const float* __restrict__ bp,
                     float* __restrict__ out)
{
    __shared__ __align__(16) _Float16 S[TM * QSTRIDE];   // 49664 B

    const int tid   = threadIdx.x;
    const int lane  = tid & 63;
    const int wv_id = tid >> 6;      // wave 0..7
    const int l15   = lane & 15;
    const int quad  = lane >> 4;
    const long token0 = (long)blockIdx.x * TM;

    // 6 GEMM1 n-tiles owned by this wave: k-section + v-low first, then
    // q-section + v-tail (order is free — all writebacks happen post-barrier2)
    const int tiles[6] = { 16 + wv_id * 3, 17 + wv_id * 3, 18 + wv_id * 3,
                           2 * wv_id, 2 * wv_id + 1, 40 + wv_id };

    // ---- stage 0: issue v-tile loads, then GEMM1 ring prologue -------------
    const float4* src = (const float4*)(v + token0 * DIMX);
    float4 t4[4];
#pragma unroll
    for (int i = 0; i < 4; ++i)
        t4[i] = src[tid + NTHREADS * i];

    // ring-8 weight buffer; prologue = first tile's 8 frags (in flight while
    // v loads land + staging stores run; drained at barrier 1)
    const f16x8* wb = (const f16x8*)Wqkv_pk + lane;
    f16x8 Wr[8];
#pragma unroll
    for (int p = 0; p < 8; ++p)
        Wr[p] = wb[(size_t)(tiles[0] * KT + p) * 64];

    // fp32 -> f16 -> S cols [0,256)
#pragma unroll
    for (int i = 0; i < 4; ++i) {
        int u = tid + NTHREADS * i;       // 0..2047 float4 slots
        int m = u >> 6;                   // token row (wave-uniform)
        int c = (u & 63) * 4;
        f16x2 lo = pkrtz(t4[i].x, t4[i].y), hi = pkrtz(t4[i].z, t4[i].w);
        f16x4 b4 = { lo.x, lo.y, hi.x, hi.y };
        *(f16x4*)&S[m * QSTRIDE + c] = b4;
    }
    __syncthreads();   // barrier 1: v tile visible in LDS

    // ---- B-fragments (v) -> registers: 2 tt x 8 kt = 16 f16x8 (64 VGPR) ---
    f16x8 vr[2][KT];
#pragma unroll
    for (int tt = 0; tt < 2; ++tt)
#pragma unroll
        for (int kt = 0; kt < KT; ++kt)
            vr[tt][kt] = *(const f16x8*)&S[(tt * 16 + l15) * QSTRIDE + kt * 32 + quad * 8];
    __syncthreads();   // barrier 2: ALL v reads done; q-section writable

    // ---- GEMM1: single pass, 6 tiles, flattened 48-step ring-8 stream ------
#pragma unroll
    for (int j = 0; j < 6; ++j) {
        f32x4 acc[2];
        acc[0] = (f32x4){0.f, 0.f, 0.f, 0.f};
        acc[1] = (f32x4){0.f, 0.f, 0.f, 0.f};
#pragma unroll
        for (int kt = 0; kt < KT; ++kt) {
            const int u = j * KT + kt;
            f16x8 w = Wr[u & 7];
            if (u + 8 < 6 * KT) {
                const int un = u + 8;
                Wr[u & 7] = wb[(size_t)(tiles[un >> 3] * KT + (un & 7)) * 64];
            }
            acc[0] = __builtin_amdgcn_mfma_f32_16x16x32_f16(w, vr[0][kt], acc[0], 0, 0, 0);
            acc[1] = __builtin_amdgcn_mfma_f32_16x16x32_f16(w, vr[1][kt], acc[1], 0, 0, 0);
        }
        // immediate writeback (v tile already consumed into registers)
#pragma unroll
        for (int tt = 0; tt < 2; ++tt) {
            f16x2 a = pkrtz(acc[tt][0], acc[tt][1]);
            f16x2 b = pkrtz(acc[tt][2], acc[tt][3]);
            f16x4 p4 = { a.x, a.y, b.x, b.y };
            *(f16x4*)&S[(tt * 16 + l15) * QSTRIDE + tiles[j] * 16 + quad * 4] = p4;
        }
    }

    // ---- GEMM2 weight prologue: 2 tiles x kt{0,1} issued before barrier 3 --
    // (latency hides under the barrier gather + attention phase)
    const f16x8* wb2 = (const f16x8*)Wp_pk + lane;
    const int nt0 = wv_id * 2;
    f16x8 W2[4];                      // ring-4, u = kt*2 + j
#pragma unroll
    for (int p = 0; p < 4; ++p)
        W2[p] = wb2[(size_t)((nt0 + (p & 1)) * KT + (p >> 1)) * 64];

    __syncthreads();   // barrier 3: q|k|vv complete in LDS

    // ---- attention: 16 threads/token = (head h, half d0); packed f16 -------
    {
        const int ta  = tid >> 4;         // token 0..31
        const int sub = tid & 15;
        const int h   = sub >> 1;
        const int d0  = (sub & 1) * 16;   // half of the 32-wide head dim
        const float scale = 0.17677669529663687f;  // 32^-0.5

        const _Float16* qrow  = &S[ta * QSTRIDE + h * HD + d0];
        const _Float16* kbase = &S[ta * QSTRIDE + 256 + d0];
        const _Float16* vbase = &S[ta * QSTRIDE + 512 + d0];

        f16x8 q0 = *(const f16x8*)qrow;
        f16x8 q1 = *(const f16x8*)(qrow + 8);

        float logits[NH];
#pragma unroll
        for (int g = 0; g < NH; ++g) {
            f16x8 k0 = *(const f16x8*)(kbase + g * HD);
            f16x8 k1 = *(const f16x8*)(kbase + g * HD + 8);
            f16x8 p  = q0 * k0;
            p += q1 * k1;
            f16x4 r4 = __builtin_shufflevector(p, p, 0, 1, 2, 3)
                     + __builtin_shufflevector(p, p, 4, 5, 6, 7);
            f16x2 r2 = __builtin_shufflevector(r4, r4, 0, 1)
                     + __builtin_shufflevector(r4, r4, 2, 3);
            logits[g] = (float)r2.x + (float)r2.y;
        }
#pragma unroll
        for (int g = 0; g < NH; ++g)
            logits[g] = (logits[g] + __shfl_xor(logits[g], 1, 64)) * scale;

        float mx = logits[0];
#pragma unroll
        for (int g = 1; g < NH; ++g) mx = fmaxf(mx, logits[g]);
        float se = 0.f;
#pragma unroll
        for (int g = 0; g < NH; ++g) { logits[g] = __expf(logits[g] - mx); se += logits[g]; }
        float inv = 1.f / se;

        f16x8 xa0 = (f16x8)(_Float16)0.f;
        f16x8 xa1 = (f16x8)(_Float16)0.f;
#pragma unroll
        for (int g = 0; g < NH; ++g) {
            _Float16 ph = (_Float16)(logits[g] * inv);
            f16x8 pw = { ph, ph, ph, ph, ph, ph, ph, ph };
            f16x8 v0 = *(const f16x8*)(vbase + g * HD);
            f16x8 v1 = *(const f16x8*)(vbase + g * HD + 8);
            xa0 += pw * v0;
            xa1 += pw * v1;
        }
        __syncthreads();   // barrier 4: all q/k reads done; overwrite q with x
        *(f16x8*)&S[ta * QSTRIDE + h * HD + d0]     = xa0;
        *(f16x8*)&S[ta * QSTRIDE + h * HD + d0 + 8] = xa1;
    }
    __syncthreads();   // barrier 5: x tile complete

    // ---- GEMM2: out = x @ Wp + bp; wave w owns n-tiles {2w, 2w+1} ----------
    {
        f32x4 acc[2][2];   // [tt][j]
#pragma unroll
        for (int tt = 0; tt < 2; ++tt)
#pragma unroll
            for (int j = 0; j < 2; ++j)
                acc[tt][j] = (f32x4){0.f, 0.f, 0.f, 0.f};

#pragma unroll
        for (int kt = 0; kt < KT; ++kt) {
            f16x8 xf[2];
#pragma unroll
            for (int tt = 0; tt < 2; ++tt)
                xf[tt] = *(const f16x8*)&S[(tt * 16 + l15) * QSTRIDE + kt * 32 + quad * 8];
#pragma unroll
            for (int j = 0; j < 2; ++j) {
                const int u = kt * 2 + j;
                f16x8 w = W2[u & 3];
                if (u + 4 < 2 * KT)
                    W2[u & 3] = wb2[(size_t)((nt0 + j) * KT + (kt + 2)) * 64];
                acc[0][j] = __builtin_amdgcn_mfma_f32_16x16x32_f16(w, xf[0], acc[0][j], 0, 0, 0);
                acc[1][j] = __builtin_amdgcn_mfma_f32_16x16x32_f16(w, xf[1], acc[1][j], 0, 0, 0);
            }
        }
#pragma unroll
        for (int j = 0; j < 2; ++j) {
            f32x4 b = *(const f32x4*)&bp[(nt0 + j) * 16 + quad * 4];
#pragma unroll
            for (int tt = 0; tt < 2; ++tt) {
                f32x4 o = acc[tt][j] + b;
                *(f32x4*)&out[(token0 + tt * 16 + l15) * DIMX + (nt0 + j) * 16 + quad * 4] = o;
            }
        }
    }
}

extern "C" void kernel_launch(void* const* d_in, const int* in_sizes, int n_in,
                              void* d_out, int out_size, void* d_ws, size_t ws_size,
                              hipStream_t stream) {
    const float* v  = (const float*)d_in[0];
    const float* Wq = (const float*)d_in[1];
    const float* Wk = (const float*)d_in[2];
    const float* Wv = (const float*)d_in[3];
    const float* Wp = (const float*)d_in[4];
    const float* bp = (const float*)d_in[5];
    float* out = (float*)d_out;

    _Float16* pk = (_Float16*)d_ws;                // 32768 frags * 16 B = 512 KB
    const _Float16* Wqkv_pk = pk;                  // 24576 frags
    const _Float16* Wp_pk   = pk + (size_t)24576 * 8;

    pack_weights<<<256, 128, 0, stream>>>(Wq, Wk, Wv, Wp, pk);

    const int ntokens = in_sizes[0] / DIMX;        // 65536
    fused_attn_mfma<<<ntokens / TM, NTHREADS, 0, stream>>>(v, Wqkv_pk, Wp_pk, bp, out);
}

// Round 2
// 171.086 us; speedup vs baseline: 1.4870x; 1.4870x over previous
//
#include <hip/hip_runtime.h>
#include <hip/hip_bf16.h>
#include <math.h>

// Fused SelfAttention (attention over the HEADS axis, per token):
//   qkv = v @ [Wq|Wk|Wv]  (65536x256 @ 256x768, f16 MFMA)
//   per-token 8x8 softmax attention over heads (packed f16 + fp32 softmax)
//   out = x @ Wp + bp       (65536x256 @ 256x256, f16 MFMA)
//
// MFMA orientation: D = A*B, A = W^T-tile (rows = output col n), B = v^T-tile
// (cols = tokens). C/D layout: col(lane&15)=token, row(quad*4+r)=n.
// R6: TM=64 / 1024 threads / 1 block/CU. Halves the per-token L2 weight
// stream (537 MB total, each frag feeds 4 MFMAs). GEMM1 is a single fused
// 3-tile pass (vf read once per kt serves 12 MFMAs); q-tile writeback is
// deferred past the v-read barrier (no two-pass split needed). Unified
// ring-8 weight prefetch covers GEMM1 (24 frags) then lands GEMM2's 8 frags
// in the same ring. Budget: acc 48 + ring 32 + vf 16 + addr ~15 < 128 VGPR
// cap (launch_bounds(1024,4)) -> no spill (R5 lesson).

#define DIMX      256
#define NH        8
#define HD        32
#define TM        64       // tokens per block
#define NTHREADS  1024     // 16 waves
#define QSTRIDE   776      // f16 units per row; 1552 B (16B aligned, banks ok)
#define KT        8        // 256/32 k-tiles
#define NT_QKV    48       // q: 0..15, k: 16..31, v: 32..47

typedef _Float16 f16x8 __attribute__((ext_vector_type(8)));
typedef _Float16 f16x4 __attribute__((ext_vector_type(4)));
typedef _Float16 f16x2 __attribute__((ext_vector_type(2)));
typedef float    f32x4 __attribute__((ext_vector_type(4)));

static __device__ __forceinline__ f16x2 pkrtz(float a, float b) {
    return (f16x2)__builtin_amdgcn_cvt_pkrtz(a, b);
}

// ---------------------------------------------------------------------------
// Prep: pack Wq|Wk|Wv and Wp into MFMA A-operand fragment order, fp32->f16.
// frag[j] = W[kt*32 + quad*8 + j][nt*16 + (lane&15)]
// packed index u = (nt*KT + kt)*64 + lane ; 8 f16 (16 B) per u, contiguous.
// ---------------------------------------------------------------------------
__global__ void pack_weights(const float* __restrict__ Wq,
                             const float* __restrict__ Wk,
                             const float* __restrict__ Wv,
                             const float* __restrict__ Wp,
                             _Float16* __restrict__ pk)
{
    const int QKV_FRAGS = NT_QKV * KT * 64;   // 24576
    int u = blockIdx.x * blockDim.x + threadIdx.x;  // 0..32767
    const float* W;
    int nt, kt, lane;
    if (u < QKV_FRAGS) {
        nt = u / (KT * 64); kt = (u / 64) % KT; lane = u % 64;
        if (nt < 16)      { W = Wq; }
        else if (nt < 32) { W = Wk; nt -= 16; }
        else              { W = Wv; nt -= 32; }
    } else {
        int u2 = u - QKV_FRAGS;
        nt = u2 / (KT * 64); kt = (u2 / 64) % KT; lane = u2 % 64;
        W = Wp;
    }
    const int n  = nt * 16 + (lane & 15);
    const int k0 = kt * 32 + (lane >> 4) * 8;
    f16x8 frag;
#pragma unroll
    for (int j = 0; j < 8; ++j)
        frag[j] = (_Float16)W[(size_t)(k0 + j) * DIMX + n];
    *(f16x8*)(pk + (size_t)u * 8) = frag;
}

// ---------------------------------------------------------------------------
// Main fused kernel. LDS: single 64x776 f16 region (99,328 B -> 1 block/CU).
//   phase A: v tile in cols [0,256); phase B: q|k|vv in cols [0,768);
//   phase C: x tile overwrites q-section cols [0,256).
// ---------------------------------------------------------------------------
__global__ __launch_bounds__(NTHREADS, 4)   // 16 waves = 4/EU, 1 block/CU, <=128 VGPR
void fused_attn_mfma(const float* __restrict__ v,
                     const _Float16* __restrict__ Wqkv_pk,
                     const _Float16* __restrict__ Wp_pk,
                     const float* __restrict__ bp,
                     float* __restrict__ out)
{
    __shared__ __align__(16) _Float16 S[TM * QSTRIDE];   // 99,328 B

    const int tid   = threadIdx.x;
    const int lane  = tid & 63;
    const int wv_id = tid >> 6;      // wave 0..15
    const int l15   = lane & 15;
    const int quad  = lane >> 4;
    const long token0 = (long)blockIdx.x * TM;

    // 3 GEMM1 n-tiles per wave: two k|v-section tiles (immediate writeback,
    // cols >= 256 never alias the v tile) + one q-section tile (deferred).
    const int tiles[3] = { 16 + 2 * wv_id, 17 + 2 * wv_id, wv_id };

    // ---- stage 0: issue v-tile loads, then ring-8 weight prologue ----------
    const float4* src = (const float4*)(v + token0 * DIMX);
    float4 t4[4];
#pragma unroll
    for (int i = 0; i < 4; ++i)
        t4[i] = src[tid + NTHREADS * i];

    // unified weight stream, 32 frags/wave: u=0..23 GEMM1 (kt=u/3, jj=u%3),
    // u=24..31 GEMM2 (kt=u-24). Ring-8: prologue = u 0..7, in flight during
    // staging stores + barrier.
    const f16x8* wb  = (const f16x8*)Wqkv_pk + lane;
    const f16x8* wb2 = (const f16x8*)Wp_pk + lane;
    f16x8 Wr[8];
#pragma unroll
    for (int p = 0; p < 8; ++p)
        Wr[p] = wb[(size_t)(tiles[p % 3] * KT + p / 3) * 64];

    // fp32 -> f16 -> S cols [0,256)
#pragma unroll
    for (int i = 0; i < 4; ++i) {
        int u = tid + NTHREADS * i;       // 0..4095 float4 slots
        int m = u >> 6;                   // token row (wave-uniform)
        int c = (u & 63) * 4;
        f16x2 lo = pkrtz(t4[i].x, t4[i].y), hi = pkrtz(t4[i].z, t4[i].w);
        f16x4 b4 = { lo.x, lo.y, hi.x, hi.y };
        *(f16x4*)&S[m * QSTRIDE + c] = b4;
    }
    __syncthreads();   // barrier 1: v tile visible in LDS

    // ---- GEMM1: single fused pass, 3 tiles x 4 tt, ring-8 weight stream ----
    f32x4 acc[3][4];   // [jj][tt] = 48 VGPR
#pragma unroll
    for (int jj = 0; jj < 3; ++jj)
#pragma unroll
        for (int tt = 0; tt < 4; ++tt)
            acc[jj][tt] = (f32x4){0.f, 0.f, 0.f, 0.f};

#pragma unroll
    for (int kt = 0; kt < KT; ++kt) {
        f16x8 vf[4];
#pragma unroll
        for (int tt = 0; tt < 4; ++tt)
            vf[tt] = *(const f16x8*)&S[(tt * 16 + l15) * QSTRIDE + kt * 32 + quad * 8];
#pragma unroll
        for (int jj = 0; jj < 3; ++jj) {
            const int u = kt * 3 + jj;
            f16x8 w = Wr[u & 7];
            const int un = u + 8;                   // compile-time constant
            if (un < 24)
                Wr[u & 7] = wb[(size_t)(tiles[un % 3] * KT + un / 3) * 64];
            else
                Wr[u & 7] = wb2[(size_t)(wv_id * KT + (un - 24)) * 64];
#pragma unroll
            for (int tt = 0; tt < 4; ++tt)
                acc[jj][tt] = __builtin_amdgcn_mfma_f32_16x16x32_f16(w, vf[tt], acc[jj][tt], 0, 0, 0);
        }
    }

    // immediate writeback of the two k|v-section tiles (no v-tile alias)
#pragma unroll
    for (int jj = 0; jj < 2; ++jj)
#pragma unroll
        for (int tt = 0; tt < 4; ++tt) {
            f16x2 a = pkrtz(acc[jj][tt][0], acc[jj][tt][1]);
            f16x2 b = pkrtz(acc[jj][tt][2], acc[jj][tt][3]);
            f16x4 p4 = { a.x, a.y, b.x, b.y };
            *(f16x4*)&S[(tt * 16 + l15) * QSTRIDE + tiles[jj] * 16 + quad * 4] = p4;
        }
    __syncthreads();   // barrier 2: ALL v-tile reads done; q-section writable

    // deferred q-tile writeback
#pragma unroll
    for (int tt = 0; tt < 4; ++tt) {
        f16x2 a = pkrtz(acc[2][tt][0], acc[2][tt][1]);
        f16x2 b = pkrtz(acc[2][tt][2], acc[2][tt][3]);
        f16x4 p4 = { a.x, a.y, b.x, b.y };
        *(f16x4*)&S[(tt * 16 + l15) * QSTRIDE + tiles[2] * 16 + quad * 4] = p4;
    }
    __syncthreads();   // barrier 3: q|k|vv complete in LDS

    // ---- attention: 16 threads/token = (head h, half d0); packed f16 -------
    {
        const int ta  = tid >> 4;         // token 0..63
        const int sub = tid & 15;
        const int h   = sub >> 1;
        const int d0  = (sub & 1) * 16;   // half of the 32-wide head dim
        const float scale = 0.17677669529663687f;  // 32^-0.5

        const _Float16* qrow  = &S[ta * QSTRIDE + h * HD + d0];
        const _Float16* kbase = &S[ta * QSTRIDE + 256 + d0];
        const _Float16* vbase = &S[ta * QSTRIDE + 512 + d0];

        f16x8 q0 = *(const f16x8*)qrow;
        f16x8 q1 = *(const f16x8*)(qrow + 8);

        float logits[NH];
#pragma unroll
        for (int g = 0; g < NH; ++g) {
            f16x8 k0 = *(const f16x8*)(kbase + g * HD);
            f16x8 k1 = *(const f16x8*)(kbase + g * HD + 8);
            f16x8 p  = q0 * k0;
            p += q1 * k1;
            f16x4 r4 = __builtin_shufflevector(p, p, 0, 1, 2, 3)
                     + __builtin_shufflevector(p, p, 4, 5, 6, 7);
            f16x2 r2 = __builtin_shufflevector(r4, r4, 0, 1)
                     + __builtin_shufflevector(r4, r4, 2, 3);
            logits[g] = (float)r2.x + (float)r2.y;
        }
#pragma unroll
        for (int g = 0; g < NH; ++g)
            logits[g] = (logits[g] + __shfl_xor(logits[g], 1, 64)) * scale;

        float mx = logits[0];
#pragma unroll
        for (int g = 1; g < NH; ++g) mx = fmaxf(mx, logits[g]);
        float se = 0.f;
#pragma unroll
        for (int g = 0; g < NH; ++g) { logits[g] = __expf(logits[g] - mx); se += logits[g]; }
        float inv = 1.f / se;

        f16x8 xa0 = (f16x8)(_Float16)0.f;
        f16x8 xa1 = (f16x8)(_Float16)0.f;
#pragma unroll
        for (int g = 0; g < NH; ++g) {
            _Float16 ph = (_Float16)(logits[g] * inv);
            f16x8 pw = { ph, ph, ph, ph, ph, ph, ph, ph };
            f16x8 v0 = *(const f16x8*)(vbase + g * HD);
            f16x8 v1 = *(const f16x8*)(vbase + g * HD + 8);
            xa0 += pw * v0;
            xa1 += pw * v1;
        }
        __syncthreads();   // barrier 4: all q/k reads done; overwrite q with x
        *(f16x8*)&S[ta * QSTRIDE + h * HD + d0]     = xa0;
        *(f16x8*)&S[ta * QSTRIDE + h * HD + d0 + 8] = xa1;
    }
    __syncthreads();   // barrier 5: x tile complete

    // ---- GEMM2: out = x @ Wp + bp; wave w owns n-tile w ----------
    // Wp frags for tile w already sit in the ring: Wr[kt] = frag kt.
    {
        f32x4 acc2[4];
#pragma unroll
        for (int tt = 0; tt < 4; ++tt)
            acc2[tt] = (f32x4){0.f, 0.f, 0.f, 0.f};

#pragma unroll
        for (int kt = 0; kt < KT; ++kt) {
            f16x8 xf[4];
#pragma unroll
            for (int tt = 0; tt < 4; ++tt)
                xf[tt] = *(const f16x8*)&S[(tt * 16 + l15) * QSTRIDE + kt * 32 + quad * 8];
            f16x8 w = Wr[kt];
#pragma unroll
            for (int tt = 0; tt < 4; ++tt)
                acc2[tt] = __builtin_amdgcn_mfma_f32_16x16x32_f16(w, xf[tt], acc2[tt], 0, 0, 0);
        }

        f32x4 b = *(const f32x4*)&bp[wv_id * 16 + quad * 4];
#pragma unroll
        for (int tt = 0; tt < 4; ++tt) {
            f32x4 o = acc2[tt] + b;
            *(f32x4*)&out[(token0 + tt * 16 + l15) * DIMX + wv_id * 16 + quad * 4] = o;
        }
    }
}

extern "C" void kernel_launch(void* const* d_in, const int* in_sizes, int n_in,
                              void* d_out, int out_size, void* d_ws, size_t ws_size,
                              hipStream_t stream) {
    const float* v  = (const float*)d_in[0];
    const float* Wq = (const float*)d_in[1];
    const float* Wk = (const float*)d_in[2];
    const float* Wv = (const float*)d_in[3];
    const float* Wp = (const float*)d_in[4];
    const float* bp = (const float*)d_in[5];
    float* out = (float*)d_out;

    _Float16* pk = (_Float16*)d_ws;                // 32768 frags * 16 B = 512 KB
    const _Float16* Wqkv_pk = pk;                  // 24576 frags
    const _Float16* Wp_pk   = pk + (size_t)24576 * 8;

    pack_weights<<<256, 128, 0, stream>>>(Wq, Wk, Wv, Wp, pk);

    const int ntokens = in_sizes[0] / DIMX;        // 65536
    fused_attn_mfma<<<ntokens / TM, NTHREADS, 0, stream>>>(v, Wqkv_pk, Wp_pk, bp, out);
}

// Round 3
// 164.721 us; speedup vs baseline: 1.5445x; 1.0386x over previous
//
#include <hip/hip_runtime.h>
#include <hip/hip_bf16.h>
#include <math.h>

// Fused SelfAttention (attention over the HEADS axis, per token):
//   qkv = v @ [Wq|Wk|Wv]  (65536x256 @ 256x768, f16 MFMA)
//   per-token 8x8 softmax attention over heads (packed f16 + fp32 softmax)
//   out = x @ Wp + bp       (65536x256 @ 256x256, f16 MFMA)
//
// MFMA orientation: D = A*B, A = W^T-tile (rows = output col n), B = v^T-tile
// (cols = tokens). C/D layout: col(lane&15)=token, row(quad*4+r)=n.
// R7: LDS-traffic retiling. Model: kernel is LDS-BW-bound (27 KB/token in R6
// -> 1.78 GB @ ~22 TB/s = 81 us ~= measured 78). Fix: split the 64 tokens
// into 2 groups of 32; wave (s=w>>1, grp=w&1) owns 6 n-tiles x 2 token-rows
// (acc still 48 VGPR) -> each wave streams only its group's B-frags:
// GEMM1 B 8->4 KB/tok, GEMM2 8->4 KB/tok. Twin waves (2s,2s+1) read the
// IDENTICAL weight-frag stream in identical order -> second read L1-hits,
// keeping L2 weight traffic ~537 MB. Ring-8 weight prefetch spans
// GEMM1 (48 frags) + GEMM2 (16 frags, first 8 preloaded in GEMM1 tail).

#define DIMX      256
#define NH        8
#define HD        32
#define TM        64       // tokens per block
#define NTHREADS  1024     // 16 waves
#define QSTRIDE   776      // f16 units per row; 1552 B (16B aligned, banks ok)
#define KT        8        // 256/32 k-tiles
#define NT_QKV    48       // q: 0..15, k: 16..31, v: 32..47

typedef _Float16 f16x8 __attribute__((ext_vector_type(8)));
typedef _Float16 f16x4 __attribute__((ext_vector_type(4)));
typedef _Float16 f16x2 __attribute__((ext_vector_type(2)));
typedef float    f32x4 __attribute__((ext_vector_type(4)));

static __device__ __forceinline__ f16x2 pkrtz(float a, float b) {
    return (f16x2)__builtin_amdgcn_cvt_pkrtz(a, b);
}

// ---------------------------------------------------------------------------
// Prep: pack Wq|Wk|Wv and Wp into MFMA A-operand fragment order, fp32->f16.
// frag[j] = W[kt*32 + quad*8 + j][nt*16 + (lane&15)]
// packed index u = (nt*KT + kt)*64 + lane ; 8 f16 (16 B) per u, contiguous.
// ---------------------------------------------------------------------------
__global__ void pack_weights(const float* __restrict__ Wq,
                             const float* __restrict__ Wk,
                             const float* __restrict__ Wv,
                             const float* __restrict__ Wp,
                             _Float16* __restrict__ pk)
{
    const int QKV_FRAGS = NT_QKV * KT * 64;   // 24576
    int u = blockIdx.x * blockDim.x + threadIdx.x;  // 0..32767
    const float* W;
    int nt, kt, lane;
    if (u < QKV_FRAGS) {
        nt = u / (KT * 64); kt = (u / 64) % KT; lane = u % 64;
        if (nt < 16)      { W = Wq; }
        else if (nt < 32) { W = Wk; nt -= 16; }
        else              { W = Wv; nt -= 32; }
    } else {
        int u2 = u - QKV_FRAGS;
        nt = u2 / (KT * 64); kt = (u2 / 64) % KT; lane = u2 % 64;
        W = Wp;
    }
    const int n  = nt * 16 + (lane & 15);
    const int k0 = kt * 32 + (lane >> 4) * 8;
    f16x8 frag;
#pragma unroll
    for (int j = 0; j < 8; ++j)
        frag[j] = (_Float16)W[(size_t)(k0 + j) * DIMX + n];
    *(f16x8*)(pk + (size_t)u * 8) = frag;
}

// ---------------------------------------------------------------------------
// Main fused kernel. LDS: single 64x776 f16 region (99,328 B -> 1 block/CU).
//   phase A: v tile in cols [0,256); phase B: q|k|vv in cols [0,768);
//   phase C: x tile overwrites q-section cols [0,256).
// ---------------------------------------------------------------------------
__global__ __launch_bounds__(NTHREADS, 4)   // 16 waves = 4/EU, 1 block/CU, <=128 VGPR
void fused_attn_mfma(const float* __restrict__ v,
                     const _Float16* __restrict__ Wqkv_pk,
                     const _Float16* __restrict__ Wp_pk,
                     const float* __restrict__ bp,
                     float* __restrict__ out)
{
    __shared__ __align__(16) _Float16 S[TM * QSTRIDE];   // 99,328 B

    const int tid   = threadIdx.x;
    const int lane  = tid & 63;
    const int wv_id = tid >> 6;      // wave 0..15
    const int l15   = lane & 15;
    const int quad  = lane >> 4;
    const long token0 = (long)blockIdx.x * TM;

    const int s8  = wv_id >> 1;      // tile-set 0..7 (shared by twin waves)
    const int grp = wv_id & 1;       // token group: rows [grp*32, grp*32+32)

    // 6 GEMM1 n-tiles per tile-set: four k|v-section tiles (immediate
    // writeback, cols >= 256 never alias the v tile) + two q-section tiles
    // (deferred past the v-read barrier).
    const int tiles[6] = { 16 + 4 * s8, 17 + 4 * s8, 18 + 4 * s8, 19 + 4 * s8,
                           2 * s8, 2 * s8 + 1 };

    // ---- stage 0: issue v-tile loads, then ring-8 weight prologue ----------
    const float4* src = (const float4*)(v + token0 * DIMX);
    float4 t4[4];
#pragma unroll
    for (int i = 0; i < 4; ++i)
        t4[i] = src[tid + NTHREADS * i];

    // unified weight stream, 64 frags/wave: u=0..47 GEMM1 (kt=u/6, j=u%6),
    // u=48..63 GEMM2 (u2=u-48: kt=u2>>1, j=u2&1). Ring-8: prologue u=0..7.
    const f16x8* wb  = (const f16x8*)Wqkv_pk + lane;
    const f16x8* wb2 = (const f16x8*)Wp_pk + lane;
    f16x8 Wr[8];
#pragma unroll
    for (int p = 0; p < 8; ++p)
        Wr[p] = wb[(size_t)(tiles[p % 6] * KT + p / 6) * 64];

    // fp32 -> f16 -> S cols [0,256)
#pragma unroll
    for (int i = 0; i < 4; ++i) {
        int u = tid + NTHREADS * i;       // 0..4095 float4 slots
        int m = u >> 6;                   // token row (wave-uniform)
        int c = (u & 63) * 4;
        f16x2 lo = pkrtz(t4[i].x, t4[i].y), hi = pkrtz(t4[i].z, t4[i].w);
        f16x4 b4 = { lo.x, lo.y, hi.x, hi.y };
        *(f16x4*)&S[m * QSTRIDE + c] = b4;
    }
    __syncthreads();   // barrier 1: v tile visible in LDS

    // ---- GEMM1: 6 tiles x 2 token-rows (own group only), ring-8 stream -----
    f32x4 acc[6][2];   // [j][t] = 48 VGPR
#pragma unroll
    for (int j = 0; j < 6; ++j)
#pragma unroll
        for (int t = 0; t < 2; ++t)
            acc[j][t] = (f32x4){0.f, 0.f, 0.f, 0.f};

#pragma unroll
    for (int kt = 0; kt < KT; ++kt) {
        f16x8 vf[2];
#pragma unroll
        for (int t = 0; t < 2; ++t)
            vf[t] = *(const f16x8*)&S[(grp * 32 + t * 16 + l15) * QSTRIDE + kt * 32 + quad * 8];
#pragma unroll
        for (int j = 0; j < 6; ++j) {
            const int u = kt * 6 + j;
            f16x8 w = Wr[u & 7];
            const int un = u + 8;                   // compile-time constant
            if (un < 48)
                Wr[u & 7] = wb[(size_t)(tiles[un % 6] * KT + un / 6) * 64];
            else {
                const int u2 = un - 48;             // 0..7: GEMM2 prologue
                Wr[u & 7] = wb2[(size_t)((2 * s8 + (u2 & 1)) * KT + (u2 >> 1)) * 64];
            }
            acc[j][0] = __builtin_amdgcn_mfma_f32_16x16x32_f16(w, vf[0], acc[j][0], 0, 0, 0);
            acc[j][1] = __builtin_amdgcn_mfma_f32_16x16x32_f16(w, vf[1], acc[j][1], 0, 0, 0);
        }
    }

    // immediate writeback of the four k|v-section tiles (no v-tile alias)
#pragma unroll
    for (int j = 0; j < 4; ++j)
#pragma unroll
        for (int t = 0; t < 2; ++t) {
            f16x2 a = pkrtz(acc[j][t][0], acc[j][t][1]);
            f16x2 b = pkrtz(acc[j][t][2], acc[j][t][3]);
            f16x4 p4 = { a.x, a.y, b.x, b.y };
            *(f16x4*)&S[(grp * 32 + t * 16 + l15) * QSTRIDE + tiles[j] * 16 + quad * 4] = p4;
        }
    __syncthreads();   // barrier 2: ALL v-tile reads done; q-section writable

    // deferred q-tile writeback
#pragma unroll
    for (int j = 4; j < 6; ++j)
#pragma unroll
        for (int t = 0; t < 2; ++t) {
            f16x2 a = pkrtz(acc[j][t][0], acc[j][t][1]);
            f16x2 b = pkrtz(acc[j][t][2], acc[j][t][3]);
            f16x4 p4 = { a.x, a.y, b.x, b.y };
            *(f16x4*)&S[(grp * 32 + t * 16 + l15) * QSTRIDE + tiles[j] * 16 + quad * 4] = p4;
        }
    __syncthreads();   // barrier 3: q|k|vv complete in LDS

    // ---- attention: 16 threads/token = (head h, half d0); packed f16 -------
    {
        const int ta  = tid >> 4;         // token 0..63
        const int sub = tid & 15;
        const int h   = sub >> 1;
        const int d0  = (sub & 1) * 16;   // half of the 32-wide head dim
        const float scale = 0.17677669529663687f;  // 32^-0.5

        const _Float16* qrow  = &S[ta * QSTRIDE + h * HD + d0];
        const _Float16* kbase = &S[ta * QSTRIDE + 256 + d0];
        const _Float16* vbase = &S[ta * QSTRIDE + 512 + d0];

        f16x8 q0 = *(const f16x8*)qrow;
        f16x8 q1 = *(const f16x8*)(qrow + 8);

        float logits[NH];
#pragma unroll
        for (int g = 0; g < NH; ++g) {
            f16x8 k0 = *(const f16x8*)(kbase + g * HD);
            f16x8 k1 = *(const f16x8*)(kbase + g * HD + 8);
            f16x8 p  = q0 * k0;
            p += q1 * k1;
            f16x4 r4 = __builtin_shufflevector(p, p, 0, 1, 2, 3)
                     + __builtin_shufflevector(p, p, 4, 5, 6, 7);
            f16x2 r2 = __builtin_shufflevector(r4, r4, 0, 1)
                     + __builtin_shufflevector(r4, r4, 2, 3);
            logits[g] = (float)r2.x + (float)r2.y;
        }
#pragma unroll
        for (int g = 0; g < NH; ++g)
            logits[g] = (logits[g] + __shfl_xor(logits[g], 1, 64)) * scale;

        float mx = logits[0];
#pragma unroll
        for (int g = 1; g < NH; ++g) mx = fmaxf(mx, logits[g]);
        float se = 0.f;
#pragma unroll
        for (int g = 0; g < NH; ++g) { logits[g] = __expf(logits[g] - mx); se += logits[g]; }
        float inv = 1.f / se;

        f16x8 xa0 = (f16x8)(_Float16)0.f;
        f16x8 xa1 = (f16x8)(_Float16)0.f;
#pragma unroll
        for (int g = 0; g < NH; ++g) {
            _Float16 ph = (_Float16)(logits[g] * inv);
            f16x8 pw = { ph, ph, ph, ph, ph, ph, ph, ph };
            f16x8 v0 = *(const f16x8*)(vbase + g * HD);
            f16x8 v1 = *(const f16x8*)(vbase + g * HD + 8);
            xa0 += pw * v0;
            xa1 += pw * v1;
        }
        __syncthreads();   // barrier 4: all q/k reads done; overwrite q with x
        *(f16x8*)&S[ta * QSTRIDE + h * HD + d0]     = xa0;
        *(f16x8*)&S[ta * QSTRIDE + h * HD + d0 + 8] = xa1;
    }
    __syncthreads();   // barrier 5: x tile complete

    // ---- GEMM2: out = x @ Wp + bp; tile-set s owns n-tiles {2s, 2s+1},
    //      wave handles its own token group only (xf 16 reads/wave) ----------
    {
        f32x4 acc2[2][2];   // [j][t]
#pragma unroll
        for (int j = 0; j < 2; ++j)
#pragma unroll
            for (int t = 0; t < 2; ++t)
                acc2[j][t] = (f32x4){0.f, 0.f, 0.f, 0.f};

#pragma unroll
        for (int kt = 0; kt < KT; ++kt) {
            f16x8 xf[2];
#pragma unroll
            for (int t = 0; t < 2; ++t)
                xf[t] = *(const f16x8*)&S[(grp * 32 + t * 16 + l15) * QSTRIDE + kt * 32 + quad * 8];
#pragma unroll
            for (int j = 0; j < 2; ++j) {
                const int u2 = kt * 2 + j;
                f16x8 w = Wr[u2 & 7];
                if (u2 + 8 < 16)   // prefetch frag (kt+4, j) into freed slot
                    Wr[u2 & 7] = wb2[(size_t)((2 * s8 + j) * KT + (kt + 4)) * 64];
                acc2[j][0] = __builtin_amdgcn_mfma_f32_16x16x32_f16(w, xf[0], acc2[j][0], 0, 0, 0);
                acc2[j][1] = __builtin_amdgcn_mfma_f32_16x16x32_f16(w, xf[1], acc2[j][1], 0, 0, 0);
            }
        }

#pragma unroll
        for (int j = 0; j < 2; ++j) {
            f32x4 b = *(const f32x4*)&bp[(2 * s8 + j) * 16 + quad * 4];
#pragma unroll
            for (int t = 0; t < 2; ++t) {
                f32x4 o = acc2[j][t] + b;
                *(f32x4*)&out[(token0 + grp * 32 + t * 16 + l15) * DIMX + (2 * s8 + j) * 16 + quad * 4] = o;
            }
        }
    }
}

extern "C" void kernel_launch(void* const* d_in, const int* in_sizes, int n_in,
                              void* d_out, int out_size, void* d_ws, size_t ws_size,
                              hipStream_t stream) {
    const float* v  = (const float*)d_in[0];
    const float* Wq = (const float*)d_in[1];
    const float* Wk = (const float*)d_in[2];
    const float* Wv = (const float*)d_in[3];
    const float* Wp = (const float*)d_in[4];
    const float* bp = (const float*)d_in[5];
    float* out = (float*)d_out;

    _Float16* pk = (_Float16*)d_ws;                // 32768 frags * 16 B = 512 KB
    const _Float16* Wqkv_pk = pk;                  // 24576 frags
    const _Float16* Wp_pk   = pk + (size_t)24576 * 8;

    pack_weights<<<256, 128, 0, stream>>>(Wq, Wk, Wv, Wp, pk);

    const int ntokens = in_sizes[0] / DIMX;        // 65536
    fused_attn_mfma<<<ntokens / TM, NTHREADS, 0, stream>>>(v, Wqkv_pk, Wp_pk, bp, out);
}